// Round 2
// baseline (6244.181 us; speedup 1.0000x reference)
//
#include <hip/hip_runtime.h>
#include <math.h>

#define L_ 4
#define D_ 512
#define H_ 2048
#define V_ 32000
#define B_ 2
#define T_ 2048
#define EPS_ 1e-5f

__device__ __forceinline__ float geluf(float x) {
    // exact gelu: 0.5*x*(1+erf(x/sqrt(2)))
    return 0.5f * x * (1.0f + erff(x * 0.70710678118654752f));
}

// ---------------- embedding gather: x[row, col] = embed[ids[row], col] ----------------
__global__ __launch_bounds__(256) void k_embed(const int* __restrict__ ids,
                                               const float* __restrict__ emb,
                                               float* __restrict__ x) {
    int idx = blockIdx.x * 256 + threadIdx.x;   // over B*T*D
    int row = idx >> 9;                          // / 512
    int col = idx & 511;
    x[idx] = emb[(long)ids[row] * D_ + col];
}

// ---------------- layernorm: one block (256 thr) per row of D=512 ----------------
__global__ __launch_bounds__(256) void k_layernorm(const float* __restrict__ x,
                                                   const float* __restrict__ s,
                                                   const float* __restrict__ b,
                                                   float* __restrict__ y) {
    long row = blockIdx.x;
    const float* xr = x + row * D_;
    int c0 = threadIdx.x, c1 = threadIdx.x + 256;
    float v0 = xr[c0], v1 = xr[c1];
    float sum = v0 + v1;
    float sq  = v0 * v0 + v1 * v1;
    #pragma unroll
    for (int off = 32; off >= 1; off >>= 1) {
        sum += __shfl_down(sum, off);
        sq  += __shfl_down(sq, off);
    }
    __shared__ float smem[8];
    int lane = threadIdx.x & 63, wid = threadIdx.x >> 6;
    if (lane == 0) { smem[wid] = sum; smem[4 + wid] = sq; }
    __syncthreads();
    if (threadIdx.x == 0) {
        float ts = smem[0] + smem[1] + smem[2] + smem[3];
        float tq = smem[4] + smem[5] + smem[6] + smem[7];
        float mu = ts / D_;
        float var = tq / D_ - mu * mu;
        smem[0] = mu;
        smem[1] = rsqrtf(var + EPS_);
    }
    __syncthreads();
    float mu = smem[0], r = smem[1];
    float* yr = y + row * D_;
    yr[c0] = (v0 - mu) * r * s[c0] + b[c0];
    yr[c1] = (v1 - mu) * r * s[c1] + b[c1];
}

// ---------------- d[row] = dot(xg[row,:], xn[row,:]) ----------------
__global__ __launch_bounds__(256) void k_rowdot(const float* __restrict__ a,
                                                const float* __restrict__ b,
                                                float* __restrict__ dv) {
    long row = blockIdx.x;
    const float* ar = a + row * D_;
    const float* br = b + row * D_;
    int c0 = threadIdx.x, c1 = threadIdx.x + 256;
    float v = ar[c0] * br[c0] + ar[c1] * br[c1];
    #pragma unroll
    for (int off = 32; off >= 1; off >>= 1) v += __shfl_down(v, off);
    __shared__ float sm[4];
    int lane = threadIdx.x & 63, wid = threadIdx.x >> 6;
    if (lane == 0) sm[wid] = v;
    __syncthreads();
    if (threadIdx.x == 0) dv[row] = sm[0] + sm[1] + sm[2] + sm[3];
}

// ---------------- softmax over row of S: logits = 2*S[t,j] - d[b,j]; P in-place ----------------
__global__ __launch_bounds__(256) void k_softmax(float* __restrict__ S,
                                                 const float* __restrict__ dvec) {
    long row = blockIdx.x;                 // 0..B*T-1
    int b = blockIdx.x >> 11;              // / T_
    float* Sr = S + row * T_;
    const float* db = dvec + (long)b * T_;
    float lv[8];
    float mx = -3.4e38f;
    #pragma unroll
    for (int i = 0; i < 8; i++) {
        int j = threadIdx.x + i * 256;
        float t = 2.0f * Sr[j] - db[j];
        lv[i] = t;
        mx = fmaxf(mx, t);
    }
    __shared__ float sm[4], sm2[4];
    int lane = threadIdx.x & 63, wid = threadIdx.x >> 6;
    #pragma unroll
    for (int off = 32; off >= 1; off >>= 1) mx = fmaxf(mx, __shfl_down(mx, off));
    if (lane == 0) sm[wid] = mx;
    __syncthreads();
    mx = fmaxf(fmaxf(sm[0], sm[1]), fmaxf(sm[2], sm[3]));
    float ssum = 0.f;
    #pragma unroll
    for (int i = 0; i < 8; i++) { lv[i] = expf(lv[i] - mx); ssum += lv[i]; }
    #pragma unroll
    for (int off = 32; off >= 1; off >>= 1) ssum += __shfl_down(ssum, off);
    if (lane == 0) sm2[wid] = ssum;
    __syncthreads();
    ssum = sm2[0] + sm2[1] + sm2[2] + sm2[3];
    float inv = 1.0f / ssum;
    #pragma unroll
    for (int i = 0; i < 8; i++) Sr[threadIdx.x + i * 256] = lv[i] * inv;
}

// ---------------- tiled fp32 GEMM: C[M,N] (+)= A[M,K] * B[K,N]  (or B^T when BTRANS) ----------------
// EPI: 0=store, 1=bias+gelu store, 2=bias+accumulate into C, 3=accumulate, 4=bias+store
template <bool BTRANS, int EPI>
__global__ __launch_bounds__(256) void k_gemm(const float* __restrict__ A,
                                              const float* __restrict__ Bp,
                                              float* __restrict__ C,
                                              const float* __restrict__ bias,
                                              int M, int N, int K,
                                              long sA, long sB, long sC) {
    const int bz = blockIdx.z;
    const float* Ab = A + (long)bz * sA;
    const float* Bb = Bp + (long)bz * sB;
    float* Cb = C + (long)bz * sC;

    __shared__ float As[16][65];
    __shared__ float Bs[16][65];

    const int tid = threadIdx.x;
    const int tx = tid & 15;
    const int ty = tid >> 4;

    const int m0 = blockIdx.y * 64;
    const int n0 = blockIdx.x * 64;

    const int a_m = tid >> 2;          // 0..63
    const int a_k = (tid & 3) << 2;    // 0,4,8,12

    float acc[4][4];
    #pragma unroll
    for (int i = 0; i < 4; i++)
        #pragma unroll
        for (int j = 0; j < 4; j++) acc[i][j] = 0.f;

    for (int k0 = 0; k0 < K; k0 += 16) {
        float4 av = *(const float4*)(Ab + (long)(m0 + a_m) * K + k0 + a_k);
        float4 bvv;
        int b_k, b_n;
        if constexpr (BTRANS) {
            // B is [N,K] row-major; Bs[k][n] = B[n][k]
            b_n = tid >> 2;
            b_k = (tid & 3) << 2;
            bvv = *(const float4*)(Bb + (long)(n0 + b_n) * K + k0 + b_k);
        } else {
            b_k = tid >> 4;
            b_n = (tid & 15) << 2;
            bvv = *(const float4*)(Bb + (long)(k0 + b_k) * N + n0 + b_n);
        }
        __syncthreads();
        As[a_k + 0][a_m] = av.x;
        As[a_k + 1][a_m] = av.y;
        As[a_k + 2][a_m] = av.z;
        As[a_k + 3][a_m] = av.w;
        if constexpr (BTRANS) {
            Bs[b_k + 0][b_n] = bvv.x;
            Bs[b_k + 1][b_n] = bvv.y;
            Bs[b_k + 2][b_n] = bvv.z;
            Bs[b_k + 3][b_n] = bvv.w;
        } else {
            Bs[b_k][b_n + 0] = bvv.x;
            Bs[b_k][b_n + 1] = bvv.y;
            Bs[b_k][b_n + 2] = bvv.z;
            Bs[b_k][b_n + 3] = bvv.w;
        }
        __syncthreads();
        #pragma unroll
        for (int kk = 0; kk < 16; kk++) {
            float a_[4], b_[4];
            #pragma unroll
            for (int i = 0; i < 4; i++) a_[i] = As[kk][ty * 4 + i];
            #pragma unroll
            for (int j = 0; j < 4; j++) b_[j] = Bs[kk][tx * 4 + j];
            #pragma unroll
            for (int i = 0; i < 4; i++)
                #pragma unroll
                for (int j = 0; j < 4; j++) acc[i][j] = fmaf(a_[i], b_[j], acc[i][j]);
        }
    }

    #pragma unroll
    for (int i = 0; i < 4; i++) {
        int gr = m0 + ty * 4 + i;
        #pragma unroll
        for (int j = 0; j < 4; j++) {
            int gc = n0 + tx * 4 + j;
            long off = (long)gr * N + gc;
            float v = acc[i][j];
            if constexpr (EPI == 0) {
                Cb[off] = v;
            } else if constexpr (EPI == 1) {
                v += bias[gc];
                Cb[off] = geluf(v);
            } else if constexpr (EPI == 2) {
                v += bias[gc];
                Cb[off] += v;
            } else if constexpr (EPI == 3) {
                Cb[off] += v;
            } else {
                v += bias[gc];
                Cb[off] = v;
            }
        }
    }
}

extern "C" void kernel_launch(void* const* d_in, const int* in_sizes, int n_in,
                              void* d_out, int out_size, void* d_ws, size_t ws_size,
                              hipStream_t stream) {
    const int*   ids   = (const int*)d_in[0];
    const float* embed = (const float*)d_in[1];
    const float* g     = (const float*)d_in[2];
    const float* W1    = (const float*)d_in[3];
    const float* b1    = (const float*)d_in[4];
    const float* W2    = (const float*)d_in[5];
    const float* b2    = (const float*)d_in[6];
    const float* ln1s  = (const float*)d_in[7];
    const float* ln1b  = (const float*)d_in[8];
    const float* ln2s  = (const float*)d_in[9];
    const float* ln2b  = (const float*)d_in[10];
    const float* lnfs  = (const float*)d_in[11];
    const float* lnfb  = (const float*)d_in[12];
    const float* headw = (const float*)d_in[13];
    const float* headb = (const float*)d_in[14];
    float* out = (float*)d_out;

    const long BT = (long)B_ * T_;   // 4096
    float* ws  = (float*)d_ws;
    float* x   = ws;                 // BT*D
    float* xn  = x  + BT * D_;       // BT*D
    float* xg  = xn + BT * D_;       // BT*D
    float* dv  = xg + BT * D_;       // BT (padded to 4096)
    float* big = dv + 4096;          // max(B*T*T, BT*H) = 8,388,608 floats (reused)

    k_embed<<<dim3(BT * D_ / 256), dim3(256), 0, stream>>>(ids, embed, x);

    for (int l = 0; l < L_; l++) {
        // --- attention ---
        k_layernorm<<<dim3(BT), dim3(256), 0, stream>>>(x, ln1s + l * D_, ln1b + l * D_, xn);
        // xg = xn @ g[l]   (NN)
        k_gemm<false, 0><<<dim3(D_ / 64, BT / 64, 1), dim3(256), 0, stream>>>(
            xn, g + (long)l * D_ * D_, xg, nullptr, (int)BT, D_, D_, 0, 0, 0);
        k_rowdot<<<dim3(BT), dim3(256), 0, stream>>>(xg, xn, dv);
        // S_b = xg_b @ xn_b^T   (NT, batched over B)
        k_gemm<true, 0><<<dim3(T_ / 64, T_ / 64, B_), dim3(256), 0, stream>>>(
            xg, xn, big, nullptr, T_, T_, D_, (long)T_ * D_, (long)T_ * D_, (long)T_ * T_);
        k_softmax<<<dim3(BT), dim3(256), 0, stream>>>(big, dv);
        // x_b += P_b @ xn_b   (NN, batched, accumulate)
        k_gemm<false, 3><<<dim3(D_ / 64, T_ / 64, B_), dim3(256), 0, stream>>>(
            big, xn, x, nullptr, T_, D_, T_, (long)T_ * T_, (long)T_ * D_, (long)T_ * D_);

        // --- ffn ---
        k_layernorm<<<dim3(BT), dim3(256), 0, stream>>>(x, ln2s + l * D_, ln2b + l * D_, xn);
        // big = gelu(xn @ W1[l] + b1[l])
        k_gemm<false, 1><<<dim3(H_ / 64, BT / 64, 1), dim3(256), 0, stream>>>(
            xn, W1 + (long)l * D_ * H_, big, b1 + (long)l * H_, (int)BT, H_, D_, 0, 0, 0);
        // x += big @ W2[l] + b2[l]
        k_gemm<false, 2><<<dim3(D_ / 64, BT / 64, 1), dim3(256), 0, stream>>>(
            big, W2 + (long)l * H_ * D_, x, b2 + (long)l * D_, (int)BT, D_, H_, 0, 0, 0);
    }

    k_layernorm<<<dim3(BT), dim3(256), 0, stream>>>(x, lnfs, lnfb, xn);
    // out = xf @ head_w + head_b
    k_gemm<false, 4><<<dim3(V_ / 64, BT / 64, 1), dim3(256), 0, stream>>>(
        xn, headw, out, headb, (int)BT, V_, D_, 0, 0, 0);
}